// Round 8
// baseline (261.250 us; speedup 1.0000x reference)
//
#include <hip/hip_runtime.h>
#include <hip/hip_bf16.h>
#include <hip/hip_fp16.h>
#include <hip/hip_fp8.h>

// DeformableAttention on MI355X.
// prep -> gemm(q) -> conv+LN+GELU+pos+sample -> gemm(K) -> gemm(V^T, via
// transposed-output GEMM) -> flash-attn v4 (BARRIER-FREE kt loop: K/V/pos all
// straight from global; fp8 rpe quad table in LDS; wave-local P; fixed-m
// softmax, l via ones-MFMA) -> gemm(out,+bias)
// R7 bug fixed: workspace layout had aob overlapping the transposed weights
// (attn clobbered Woutt before the final GEMM) — restored disjoint layout.

#define EPS_ 1e-5f
#define ASCALE 0.17677669529663687f      // 1/sqrt(32)
#define LOG2E  1.4426950408889634f

typedef __attribute__((ext_vector_type(8))) short bf16x8;
typedef __attribute__((ext_vector_type(4))) float f32x4;

__device__ __forceinline__ short f2bf(float f) {
  union { float f; unsigned u; } v; v.f = f;
  unsigned r = (v.u + 0x7fffu + ((v.u >> 16) & 1u)) >> 16;  // RNE
  return (short)r;
}
__device__ __forceinline__ unsigned pk2bf(float a, float b) {
  union { __hip_bfloat162 h; unsigned u; } v;
  v.h = __float22bfloat162_rn(make_float2(a, b));
  return v.u;
}
__device__ __forceinline__ float exp2_fast(float x) {
  return __builtin_amdgcn_exp2f(x);
}

// ---------------------------------------------------------------------------
// Weight prep: Wkvt[n][k]=bf16(Wkv[k][n]); Woutt, Wqt likewise.
// ---------------------------------------------------------------------------
__global__ __launch_bounds__(256) void prep_weights(
    const float* __restrict__ Wkv, const float* __restrict__ Wout,
    const float* __restrict__ Wq, short* __restrict__ Wkvt,
    short* __restrict__ Woutt, short* __restrict__ Wqt)
{
  int bid = blockIdx.x, k = threadIdx.x;
  if (bid < 512) Wkvt[bid * 256 + k] = f2bf(Wkv[k * 512 + bid]);
  else if (bid < 768) { int n = bid - 512; Woutt[n * 256 + k] = f2bf(Wout[k * 256 + n]); }
  else { int n = bid - 768; Wqt[n * 256 + k] = f2bf(Wq[k * 256 + n]); }
}

// ---------------------------------------------------------------------------
// bf16 MFMA GEMM: C[M,N] = A[M,256] @ Bt[N,256]^T (+bias).
// Reg-prefetch + double-buffered LDS -> ONE barrier per K-chunk.
// ---------------------------------------------------------------------------
__global__ __launch_bounds__(256) void gemm_bf16(
    const short* __restrict__ Ab, const float* __restrict__ Af,
    const short* __restrict__ Bt,
    float* __restrict__ Cf, short* __restrict__ Cb,
    const float* __restrict__ bias, int N)
{
  __shared__ __align__(16) short As[2][64 * 40];
  __shared__ __align__(16) short Bs[2][64 * 40];
  const int t = threadIdx.x;
  const int n0 = blockIdx.x << 6, m0 = blockIdx.y << 6;
  const int wv = t >> 6, l16 = t & 15, quad = (t & 63) >> 4;
  const int row = t >> 2, koff = (t & 3) << 3;

  auto loadA = [&](int k0) -> bf16x8 {
    if (Af) {
      const float* src = &Af[(size_t)(m0 + row) * 256 + k0 + koff];
      float4 f0 = *(const float4*)src;
      float4 f1 = *(const float4*)(src + 4);
      union { unsigned u[4]; bf16x8 v; } c;
      c.u[0] = pk2bf(f0.x, f0.y); c.u[1] = pk2bf(f0.z, f0.w);
      c.u[2] = pk2bf(f1.x, f1.y); c.u[3] = pk2bf(f1.z, f1.w);
      return c.v;
    }
    return *(const bf16x8*)&Ab[(size_t)(m0 + row) * 256 + k0 + koff];
  };

  f32x4 acc[4] = {};
  bf16x8 av = loadA(0);
  bf16x8 bv = *(const bf16x8*)&Bt[(size_t)(n0 + row) * 256 + koff];
  int pb = 0;
  for (int k0 = 0; k0 < 256; k0 += 32, pb ^= 1) {
    *(bf16x8*)&As[pb][row * 40 + koff] = av;
    *(bf16x8*)&Bs[pb][row * 40 + koff] = bv;
    __syncthreads();
    if (k0 + 32 < 256) {  // prefetch next chunk into regs during MFMA
      av = loadA(k0 + 32);
      bv = *(const bf16x8*)&Bt[(size_t)(n0 + row) * 256 + k0 + 32 + koff];
    }
    bf16x8 a = *(const bf16x8*)&As[pb][((wv << 4) + l16) * 40 + (quad << 3)];
#pragma unroll
    for (int jt = 0; jt < 4; jt++) {
      bf16x8 bb = *(const bf16x8*)&Bs[pb][((jt << 4) + l16) * 40 + (quad << 3)];
      acc[jt] = __builtin_amdgcn_mfma_f32_16x16x32_bf16(a, bb, acc[jt], 0, 0, 0);
    }
  }
#pragma unroll
  for (int jt = 0; jt < 4; jt++) {
#pragma unroll
    for (int r = 0; r < 4; r++) {
      int mrow = m0 + (wv << 4) + (quad << 2) + r;
      int ncol = n0 + (jt << 4) + l16;
      float v = acc[jt][r];
      if (bias) v += bias[ncol];
      if (Cf) Cf[(size_t)mrow * N + ncol] = v;
      else    Cb[(size_t)mrow * N + ncol] = f2bf(v);
    }
  }
}

// ---------------------------------------------------------------------------
// Fused: conv5x5 depthwise + LN(128) + GELU + @Woff + tanh -> pos, then
// grid_sample of this pixel's group channels -> xs (bf16). Wave per (b,g,pix).
// ---------------------------------------------------------------------------
__global__ __launch_bounds__(256) void conv_pos_sample_kernel(
    const float* __restrict__ q, const float* __restrict__ conv_w,
    const float* __restrict__ conv_b, const float* __restrict__ ln_g,
    const float* __restrict__ ln_b, const float* __restrict__ Woff,
    float* __restrict__ pos, short* __restrict__ xsb)
{
  const int p = (blockIdx.x << 2) + (threadIdx.x >> 6);
  const int lane = threadIdx.x & 63;
  const int bg = p >> 10, pix = p & 1023;
  const int hh = pix >> 5, ww = pix & 31;
  const int b = bg >> 1, g = bg & 1;
  const int c0 = lane << 1;

  float2 cb = *(const float2*)&conv_b[c0];
  float a0 = cb.x, a1 = cb.y;
  const float* w0 = conv_w + c0 * 25;
  const float* w1 = w0 + 25;
#pragma unroll
  for (int dy = 0; dy < 5; dy++) {
    int y = hh + dy - 2;
    if ((unsigned)y < 32u) {
#pragma unroll
      for (int dx = 0; dx < 5; dx++) {
        int x = ww + dx - 2;
        if ((unsigned)x < 32u) {
          float2 qv = *(const float2*)&q[(size_t)((b << 10) + (y << 5) + x) * 256 + (g << 7) + c0];
          a0 = fmaf(qv.x, w0[dy * 5 + dx], a0);
          a1 = fmaf(qv.y, w1[dy * 5 + dx], a1);
        }
      }
    }
  }
  float s1 = a0 + a1, s2 = a0 * a0 + a1 * a1;
#pragma unroll
  for (int o = 32; o; o >>= 1) { s1 += __shfl_xor(s1, o); s2 += __shfl_xor(s2, o); }
  float mu = s1 * (1.f / 128.f);
  float inv = rsqrtf(fmaf(-mu, mu, s2 * (1.f / 128.f)) + EPS_);
  float2 lg = *(const float2*)&ln_g[c0];
  float2 lb = *(const float2*)&ln_b[c0];
  float v0 = (a0 - mu) * inv * lg.x + lb.x;
  float v1 = (a1 - mu) * inv * lg.y + lb.y;
  float ge0 = 0.5f * v0 * (1.f + erff(v0 * 0.70710678118654752f));
  float ge1 = 0.5f * v1 * (1.f + erff(v1 * 0.70710678118654752f));
  float2 W0 = *(const float2*)&Woff[c0 * 2];
  float2 W1 = *(const float2*)&Woff[c0 * 2 + 2];
  float o0 = ge0 * W0.x + ge1 * W1.x;
  float o1 = ge0 * W0.y + ge1 * W1.y;
#pragma unroll
  for (int o = 32; o; o >>= 1) { o0 += __shfl_xor(o0, o); o1 += __shfl_xor(o1, o); }
  float py = tanhf(o0) * 0.0625f + ((hh + 0.5f) * 0.0625f - 1.f);
  float px = tanhf(o1) * 0.0625f + ((ww + 0.5f) * 0.0625f - 1.f);
  if (lane == 0)
    ((float2*)pos)[(bg << 10) + pix] = make_float2(py, px);

  float x = (px + 1.f) * 15.5f;
  float y = (py + 1.f) * 15.5f;
  float x0f = floorf(x), y0f = floorf(y);
  int ix0 = (int)x0f, iy0 = (int)y0f;
  float fx = x - x0f, fy = y - y0f;
  float ac0 = 0.f, ac1 = 0.f;
#pragma unroll
  for (int dy = 0; dy < 2; dy++) {
#pragma unroll
    for (int dx = 0; dx < 2; dx++) {
      int yi = iy0 + dy, xi = ix0 + dx;
      float w = (dy ? fy : 1.f - fy) * (dx ? fx : 1.f - fx);
      if ((unsigned)yi < 32u && (unsigned)xi < 32u) {
        float2 qv = *(const float2*)&q[(size_t)((b << 10) + (yi << 5) + xi) * 256 + (g << 7) + c0];
        ac0 = fmaf(w, qv.x, ac0);
        ac1 = fmaf(w, qv.y, ac1);
      }
    }
  }
  *(unsigned*)&xsb[(size_t)((b << 10) + pix) * 256 + (g << 7) + c0] = pk2bf(ac0, ac1);
}

// ---------------------------------------------------------------------------
// Fused attention v4: BARRIER-FREE kt loop.
// Block = (64-row i-tile, head, batch), grid 1024.  LDS = fp8 rpe quad table
// (16 KB, staged once, single barrier) + wave-local P (9.2 KB) -> ~26 KB,
// 6 blocks/CU.  Per kt, everything comes straight from global (L1/L2-hot):
// K B-frags from kb[m][256], V B-frags from pre-transposed vtg[d][m]
// (produced by a transposed-output GEMM), pos from global.  No __syncthreads
// in the loop -> waves pipeline independently across all pipes.
// ---------------------------------------------------------------------------
__global__ __launch_bounds__(256, 6) void attn_kernel(
    const float* __restrict__ q, const short* __restrict__ kb,
    const short* __restrict__ vtg, const float* __restrict__ pos,
    const float* __restrict__ rpe, short* __restrict__ ao)
{
  const int it = blockIdx.x, h = blockIdx.y, b = blockIdx.z;
  const int g = h >> 2, t = threadIdx.x;
  const int wv = t >> 6, l16 = t & 15, quad = (t & 63) >> 4;

  __shared__ __align__(16) short PL[64 * 72];       // P (wave-local rows)
  __shared__ __align__(16) unsigned rpe8[64 * 64];  // fp8 quad per point

  // ---- stage fp8 rpe quad table (origin +31; reachable window is 64x64)
  {
    const float* rp = rpe + h * 3969;
    for (int i = t; i < 4096; i += 256) {
      int ty = i >> 6, tx = i & 63;
      float v00 = 0.f, v10 = 0.f, v01 = 0.f, v11 = 0.f;
      if (tx <= 62) {
        if (ty <= 62) v00 = rp[ty * 63 + tx] * LOG2E;
        if (ty <= 61) v10 = rp[(ty + 1) * 63 + tx] * LOG2E;
      }
      if (tx <= 61) {
        if (ty <= 62) v01 = rp[ty * 63 + tx + 1] * LOG2E;
        if (ty <= 61) v11 = rp[(ty + 1) * 63 + tx + 1] * LOG2E;
      }
      __hip_fp8x2_e4m3 elo(make_float2(v00, v10));   // y-pair at x0
      __hip_fp8x2_e4m3 ehi(make_float2(v01, v11));   // y-pair at x0+1
      rpe8[i] = (unsigned)(unsigned short)elo.__x |
                ((unsigned)(unsigned short)ehi.__x << 16);
    }
  }

  // ---- Q A-frag from global (once), scaled by ASCALE*LOG2E
  const int row0 = (it << 6) + (wv << 4);
  bf16x8 aq;
  {
    const float* src = q + (size_t)((b << 10) + row0 + l16) * 256 + (h << 5) + (quad << 3);
    float4 f0 = *(const float4*)src;
    float4 f1 = *(const float4*)(src + 4);
    const float sc = ASCALE * LOG2E;
    union { unsigned u[4]; bf16x8 v; } c;
    c.u[0] = pk2bf(f0.x * sc, f0.y * sc); c.u[1] = pk2bf(f0.z * sc, f0.w * sc);
    c.u[2] = pk2bf(f1.x * sc, f1.y * sc); c.u[3] = pk2bf(f1.z * sc, f1.w * sc);
    aq = c.v;
  }

  // sampling coords (origin +31): wave's 16 rows share one raster row
  const float ayc = 15.5f * (((row0 >> 5) + 0.5f) * 0.0625f - 1.f) + 31.f;
  float ax[4];
#pragma unroll
  for (int r = 0; r < 4; r++) {
    int ix = (row0 & 31) + (quad << 2) + r;
    ax[r] = 15.5f * ((ix + 0.5f) * 0.0625f - 1.f) + 31.f;
  }

  bf16x8 vones;
#pragma unroll
  for (int i = 0; i < 8; i++) vones[i] = (short)0x3F80;  // bf16 1.0

  f32x4 Oacc[2] = {};
  f32x4 lacc = {};

  // base pointers for this (b,h)
  const short* kbB = kb + (size_t)(b << 10) * 256 + (h << 5) + (quad << 3);
  const short* vtB = vtg + (size_t)(h << 5) * 8192 + (b << 10) + (quad << 3);
  const float2* posB = ((const float2*)pos) + (((b << 1) + g) << 10) + l16;

  __syncthreads();  // rpe8 table ready; ONLY barrier in the kernel

  for (int kt = 0; kt < 16; kt++) {
    const int jb = kt << 6;

    // ---- QK^T: K B-frags straight from global, 4 MFMA
    f32x4 S[4];
#pragma unroll
    for (int jt = 0; jt < 4; jt++) {
      bf16x8 bk = *(const bf16x8*)&kbB[(size_t)(jb + (jt << 4) + l16) * 256];
      f32x4 z = {};
      S[jt] = __builtin_amdgcn_mfma_f32_16x16x32_bf16(aq, bk, z, 0, 0, 0);
    }

    // ---- bias sample (1 b32 LDS gather/sample) + p = exp2(S+bias)
    unsigned pu[4][2];
#pragma unroll
    for (int jt = 0; jt < 4; jt++) {
      float2 pj = posB[jb + (jt << 4)];
      float ys = ayc - 15.5f * pj.x;
      float y0f = floorf(ys);
      float fy = ys - y0f;
      int ybase = (int)y0f << 6;
      float bx = -15.5f * pj.y;
      float pv[4];
#pragma unroll
      for (int r = 0; r < 4; r++) {
        float sx = ax[r] + bx;
        float x0f = floorf(sx);
        float fx = sx - x0f;
        unsigned u = rpe8[ybase + (int)x0f];
        __hip_fp8x2_e4m3 plo, phi;
        plo.__x = (__hip_fp8x2_storage_t)(unsigned short)(u & 0xffffu);
        phi.__x = (__hip_fp8x2_storage_t)(unsigned short)(u >> 16);
        float2 ga = (float2)plo;   // (g00, g10)
        float2 gb = (float2)phi;   // (g01, g11)
        float h0 = fmaf(fx, gb.x - ga.x, ga.x);
        float h1 = fmaf(fx, gb.y - ga.y, ga.y);
        float bias = fmaf(fy, h1 - h0, h0);
        pv[r] = exp2_fast(S[jt][r] + bias);
      }
      pu[jt][0] = pk2bf(pv[0], pv[1]);
      pu[jt][1] = pk2bf(pv[2], pv[3]);
    }

    // ---- wave-local P write -> A-frag read (no barrier needed)
#pragma unroll
    for (int jt = 0; jt < 4; jt++) {
      int cb = (jt << 4) + l16;
      int rb = ((wv << 4) + (quad << 2)) * 72 + cb;
      PL[rb]       = (short)(pu[jt][0] & 0xffff);
      PL[rb + 72]  = (short)(pu[jt][0] >> 16);
      PL[rb + 144] = (short)(pu[jt][1] & 0xffff);
      PL[rb + 216] = (short)(pu[jt][1] >> 16);
    }
    bf16x8 pa0 = *(const bf16x8*)&PL[((wv << 4) + l16) * 72 + (quad << 3)];
    bf16x8 pa1 = *(const bf16x8*)&PL[((wv << 4) + l16) * 72 + 32 + (quad << 3)];

    // ---- PV: V B-frags straight from pre-transposed global, 4+2 MFMA
#pragma unroll
    for (int dt = 0; dt < 2; dt++) {
      bf16x8 vb0 = *(const bf16x8*)&vtB[(size_t)((dt << 4) + l16) * 8192 + jb];
      bf16x8 vb1 = *(const bf16x8*)&vtB[(size_t)((dt << 4) + l16) * 8192 + jb + 32];
      Oacc[dt] = __builtin_amdgcn_mfma_f32_16x16x32_bf16(pa0, vb0, Oacc[dt], 0, 0, 0);
      Oacc[dt] = __builtin_amdgcn_mfma_f32_16x16x32_bf16(pa1, vb1, Oacc[dt], 0, 0, 0);
    }
    lacc = __builtin_amdgcn_mfma_f32_16x16x32_bf16(pa0, vones, lacc, 0, 0, 0);
    lacc = __builtin_amdgcn_mfma_f32_16x16x32_bf16(pa1, vones, lacc, 0, 0, 0);
  }

  // ---- epilogue -> ao bf16
#pragma unroll
  for (int r = 0; r < 4; r++) {
    float inv = 1.f / lacc[r];
    int row = row0 + (quad << 2) + r;
#pragma unroll
    for (int dt = 0; dt < 2; dt++) {
      ao[(size_t)((b << 10) + row) * 256 + (h << 5) + (dt << 4) + l16] =
          f2bf(Oacc[dt][r] * inv);
    }
  }
}

// ---------------------------------------------------------------------------
extern "C" void kernel_launch(void* const* d_in, const int* in_sizes, int n_in,
                              void* d_out, int out_size, void* d_ws, size_t ws_size,
                              hipStream_t stream) {
  (void)in_sizes; (void)n_in; (void)out_size; (void)ws_size;
  const float* x      = (const float*)d_in[0];
  const float* Wq     = (const float*)d_in[1];
  const float* Wkv    = (const float*)d_in[2];
  const float* conv_w = (const float*)d_in[3];
  const float* conv_b = (const float*)d_in[4];
  const float* ln_g   = (const float*)d_in[5];
  const float* ln_b   = (const float*)d_in[6];
  const float* Woff   = (const float*)d_in[7];
  const float* rpe    = (const float*)d_in[8];
  const float* Wout   = (const float*)d_in[9];
  const float* bout   = (const float*)d_in[10];
  float* out = (float*)d_out;

  // disjoint workspace layout (float-slot offsets; bf16 arrays use 2B/slot*2)
  float* ws    = (float*)d_ws;
  float* q     = ws;                        // [0,       2097152)
  float* pos   = ws + 2097152;              // [2097152, 2129920)
  short* kb    = (short*)(ws + 2129920);    // [2129920, 3178496) 8192x256 bf16
  short* vtg   = (short*)(ws + 3178496);    // [3178496, 4227072) 256x8192 bf16
  short* xsb   = (short*)(ws + 4227072);    // [4227072, 5275648) 8192x256 bf16
  short* aob   = (short*)(ws + 5275648);    // [5275648, 6324224) 8192x256 bf16
  short* Wkvt  = (short*)(ws + 6324224);    // [6324224, 6389760) 512x256 bf16
  short* Woutt = (short*)(ws + 6389760);    // [6389760, 6422528) 256x256 bf16
  short* Wqt   = (short*)(ws + 6422528);    // [6422528, 6455296) 256x256 bf16

  prep_weights<<<1024, 256, 0, stream>>>(Wkv, Wout, Wq, Wkvt, Woutt, Wqt);
  // 1. q = x @ Wq (bf16 MFMA, f32 A staged+converted, f32 out)
  gemm_bf16<<<dim3(4, 128), 256, 0, stream>>>(nullptr, x, Wqt, q, nullptr, nullptr, 256);
  // 2+3. conv + LN + GELU + Woff + tanh -> pos, fused grid_sample -> xs
  conv_pos_sample_kernel<<<4096, 256, 0, stream>>>(q, conv_w, conv_b, ln_g, ln_b,
                                                   Woff, pos, xsb);
  // 4a. K = xs @ Wkv[:, :256]   (rows 0..255 of Wkvt)
  gemm_bf16<<<dim3(4, 128), 256, 0, stream>>>(xsb, nullptr, Wkvt, nullptr, kb, nullptr, 256);
  // 4b. V^T = Wkv[:, 256:]^T @ xs^T  (transposed-output GEMM: M=256, N=8192)
  gemm_bf16<<<dim3(128, 4), 256, 0, stream>>>(Wkvt + 256 * 256, nullptr, xsb,
                                              nullptr, vtg, nullptr, 8192);
  // 5. fused attention v4 (barrier-free kt loop) -> ao (bf16)
  attn_kernel<<<dim3(16, 8, 8), 256, 0, stream>>>(q, kb, vtg, pos, rpe, aob);
  // 6. out = ao @ Wout + bout (bf16 MFMA, f32 out)
  gemm_bf16<<<dim3(4, 128), 256, 0, stream>>>(aob, nullptr, Woutt, out, nullptr, bout, 256);
}

// Round 9
// 243.677 us; speedup vs baseline: 1.0721x; 1.0721x over previous
//
#include <hip/hip_runtime.h>
#include <hip/hip_bf16.h>
#include <hip/hip_fp16.h>
#include <hip/hip_fp8.h>

// DeformableAttention on MI355X.
// prep -> gemm(q) -> conv+LN+GELU+pos+sample -> gemm(K, frag-packed out) ->
// gemm(V^T, frag-packed out) -> flash-attn v5 (barrier-free kt loop; K/V
// MFMA operands loaded as CONTIGUOUS 1KB fragment-packed wave loads; fp8 rpe
// quad table in LDS; wave-local P; fixed-m softmax, l via ones-MFMA)
// -> gemm(out,+bias)

#define EPS_ 1e-5f
#define ASCALE 0.17677669529663687f      // 1/sqrt(32)
#define LOG2E  1.4426950408889634f

typedef __attribute__((ext_vector_type(8))) short bf16x8;
typedef __attribute__((ext_vector_type(4))) float f32x4;

__device__ __forceinline__ short f2bf(float f) {
  union { float f; unsigned u; } v; v.f = f;
  unsigned r = (v.u + 0x7fffu + ((v.u >> 16) & 1u)) >> 16;  // RNE
  return (short)r;
}
__device__ __forceinline__ unsigned pk2bf(float a, float b) {
  union { __hip_bfloat162 h; unsigned u; } v;
  v.h = __float22bfloat162_rn(make_float2(a, b));
  return v.u;
}
__device__ __forceinline__ float exp2_fast(float x) {
  return __builtin_amdgcn_exp2f(x);
}

// ---------------------------------------------------------------------------
// Weight prep: Wkvt[n][k]=bf16(Wkv[k][n]); Woutt, Wqt likewise.
// ---------------------------------------------------------------------------
__global__ __launch_bounds__(256) void prep_weights(
    const float* __restrict__ Wkv, const float* __restrict__ Wout,
    const float* __restrict__ Wq, short* __restrict__ Wkvt,
    short* __restrict__ Woutt, short* __restrict__ Wqt)
{
  int bid = blockIdx.x, k = threadIdx.x;
  if (bid < 512) Wkvt[bid * 256 + k] = f2bf(Wkv[k * 512 + bid]);
  else if (bid < 768) { int n = bid - 512; Woutt[n * 256 + k] = f2bf(Wout[k * 256 + n]); }
  else { int n = bid - 768; Wqt[n * 256 + k] = f2bf(Wq[k * 256 + n]); }
}

// ---------------------------------------------------------------------------
// bf16 MFMA GEMM: C[M,N] = A[M,256] @ Bt[N,256]^T (+bias).
// Reg-prefetch + double-buffered LDS -> ONE barrier per K-chunk.
// mode 0: normal row-major out (Cf f32 or Cb bf16)
// mode 1: K fragment-packed out (Cb; consumer = attn QK B-frags)
// mode 2: V^T fragment-packed out (Cb; consumer = attn PV B-frags)
// Frag layout: element (n,k) of a 16x32 B-frag at frag*512 + lane*8 + (k&7),
// lane = n + 16*(k>>3)  ->  wave load = base + lane*16B, fully coalesced.
// ---------------------------------------------------------------------------
__global__ __launch_bounds__(256) void gemm_bf16(
    const short* __restrict__ Ab, const float* __restrict__ Af,
    const short* __restrict__ Bt,
    float* __restrict__ Cf, short* __restrict__ Cb,
    const float* __restrict__ bias, int N, int mode)
{
  __shared__ __align__(16) short As[2][64 * 40];
  __shared__ __align__(16) short Bs[2][64 * 40];
  const int t = threadIdx.x;
  const int n0 = blockIdx.x << 6, m0 = blockIdx.y << 6;
  const int wv = t >> 6, l16 = t & 15, quad = (t & 63) >> 4;
  const int row = t >> 2, koff = (t & 3) << 3;

  auto loadA = [&](int k0) -> bf16x8 {
    if (Af) {
      const float* src = &Af[(size_t)(m0 + row) * 256 + k0 + koff];
      float4 f0 = *(const float4*)src;
      float4 f1 = *(const float4*)(src + 4);
      union { unsigned u[4]; bf16x8 v; } c;
      c.u[0] = pk2bf(f0.x, f0.y); c.u[1] = pk2bf(f0.z, f0.w);
      c.u[2] = pk2bf(f1.x, f1.y); c.u[3] = pk2bf(f1.z, f1.w);
      return c.v;
    }
    return *(const bf16x8*)&Ab[(size_t)(m0 + row) * 256 + k0 + koff];
  };

  f32x4 acc[4] = {};
  bf16x8 av = loadA(0);
  bf16x8 bv = *(const bf16x8*)&Bt[(size_t)(n0 + row) * 256 + koff];
  int pb = 0;
  for (int k0 = 0; k0 < 256; k0 += 32, pb ^= 1) {
    *(bf16x8*)&As[pb][row * 40 + koff] = av;
    *(bf16x8*)&Bs[pb][row * 40 + koff] = bv;
    __syncthreads();
    if (k0 + 32 < 256) {  // prefetch next chunk into regs during MFMA
      av = loadA(k0 + 32);
      bv = *(const bf16x8*)&Bt[(size_t)(n0 + row) * 256 + k0 + 32 + koff];
    }
    bf16x8 a = *(const bf16x8*)&As[pb][((wv << 4) + l16) * 40 + (quad << 3)];
#pragma unroll
    for (int jt = 0; jt < 4; jt++) {
      bf16x8 bb = *(const bf16x8*)&Bs[pb][((jt << 4) + l16) * 40 + (quad << 3)];
      acc[jt] = __builtin_amdgcn_mfma_f32_16x16x32_bf16(a, bb, acc[jt], 0, 0, 0);
    }
  }
#pragma unroll
  for (int jt = 0; jt < 4; jt++) {
#pragma unroll
    for (int r = 0; r < 4; r++) {
      int mrow = m0 + (wv << 4) + (quad << 2) + r;
      int ncol = n0 + (jt << 4) + l16;
      float v = acc[jt][r];
      if (mode == 0) {
        if (bias) v += bias[ncol];
        if (Cf) Cf[(size_t)mrow * N + ncol] = v;
        else    Cb[(size_t)mrow * N + ncol] = f2bf(v);
      } else if (mode == 1) {
        // K pack: mrow = token (b*1024+j), ncol = 32h+d
        int b = mrow >> 10, j = mrow & 1023;
        int h = ncol >> 5, d = ncol & 31;
        size_t frag = ((((size_t)(b << 3) + h) << 4) + (j >> 6)) * 4 + ((j >> 4) & 3);
        Cb[(frag << 9) + ((((j & 15) | ((d >> 3) << 4))) << 3) + (d & 7)] = f2bf(v);
      } else {
        // V^T pack: mrow = 32h+d, ncol = token (b*1024+j)
        int h = mrow >> 5, d = mrow & 31;
        int b = ncol >> 10, j = ncol & 1023;
        size_t frag = (((((size_t)(b << 3) + h) << 4) + (j >> 6)) * 2 + ((d >> 4) & 1)) * 2 + ((j >> 5) & 1);
        Cb[(frag << 9) + ((((d & 15) | (((j >> 3) & 3) << 4))) << 3) + (j & 7)] = f2bf(v);
      }
    }
  }
}

// ---------------------------------------------------------------------------
// Fused: conv5x5 depthwise + LN(128) + GELU + @Woff + tanh -> pos, then
// grid_sample of this pixel's group channels -> xs (bf16). Wave per (b,g,pix).
// ---------------------------------------------------------------------------
__global__ __launch_bounds__(256) void conv_pos_sample_kernel(
    const float* __restrict__ q, const float* __restrict__ conv_w,
    const float* __restrict__ conv_b, const float* __restrict__ ln_g,
    const float* __restrict__ ln_b, const float* __restrict__ Woff,
    float* __restrict__ pos, short* __restrict__ xsb)
{
  const int p = (blockIdx.x << 2) + (threadIdx.x >> 6);
  const int lane = threadIdx.x & 63;
  const int bg = p >> 10, pix = p & 1023;
  const int hh = pix >> 5, ww = pix & 31;
  const int b = bg >> 1, g = bg & 1;
  const int c0 = lane << 1;

  float2 cb = *(const float2*)&conv_b[c0];
  float a0 = cb.x, a1 = cb.y;
  const float* w0 = conv_w + c0 * 25;
  const float* w1 = w0 + 25;
#pragma unroll
  for (int dy = 0; dy < 5; dy++) {
    int y = hh + dy - 2;
    if ((unsigned)y < 32u) {
#pragma unroll
      for (int dx = 0; dx < 5; dx++) {
        int x = ww + dx - 2;
        if ((unsigned)x < 32u) {
          float2 qv = *(const float2*)&q[(size_t)((b << 10) + (y << 5) + x) * 256 + (g << 7) + c0];
          a0 = fmaf(qv.x, w0[dy * 5 + dx], a0);
          a1 = fmaf(qv.y, w1[dy * 5 + dx], a1);
        }
      }
    }
  }
  float s1 = a0 + a1, s2 = a0 * a0 + a1 * a1;
#pragma unroll
  for (int o = 32; o; o >>= 1) { s1 += __shfl_xor(s1, o); s2 += __shfl_xor(s2, o); }
  float mu = s1 * (1.f / 128.f);
  float inv = rsqrtf(fmaf(-mu, mu, s2 * (1.f / 128.f)) + EPS_);
  float2 lg = *(const float2*)&ln_g[c0];
  float2 lb = *(const float2*)&ln_b[c0];
  float v0 = (a0 - mu) * inv * lg.x + lb.x;
  float v1 = (a1 - mu) * inv * lg.y + lb.y;
  float ge0 = 0.5f * v0 * (1.f + erff(v0 * 0.70710678118654752f));
  float ge1 = 0.5f * v1 * (1.f + erff(v1 * 0.70710678118654752f));
  float2 W0 = *(const float2*)&Woff[c0 * 2];
  float2 W1 = *(const float2*)&Woff[c0 * 2 + 2];
  float o0 = ge0 * W0.x + ge1 * W1.x;
  float o1 = ge0 * W0.y + ge1 * W1.y;
#pragma unroll
  for (int o = 32; o; o >>= 1) { o0 += __shfl_xor(o0, o); o1 += __shfl_xor(o1, o); }
  float py = tanhf(o0) * 0.0625f + ((hh + 0.5f) * 0.0625f - 1.f);
  float px = tanhf(o1) * 0.0625f + ((ww + 0.5f) * 0.0625f - 1.f);
  if (lane == 0)
    ((float2*)pos)[(bg << 10) + pix] = make_float2(py, px);

  float x = (px + 1.f) * 15.5f;
  float y = (py + 1.f) * 15.5f;
  float x0f = floorf(x), y0f = floorf(y);
  int ix0 = (int)x0f, iy0 = (int)y0f;
  float fx = x - x0f, fy = y - y0f;
  float ac0 = 0.f, ac1 = 0.f;
#pragma unroll
  for (int dy = 0; dy < 2; dy++) {
#pragma unroll
    for (int dx = 0; dx < 2; dx++) {
      int yi = iy0 + dy, xi = ix0 + dx;
      float w = (dy ? fy : 1.f - fy) * (dx ? fx : 1.f - fx);
      if ((unsigned)yi < 32u && (unsigned)xi < 32u) {
        float2 qv = *(const float2*)&q[(size_t)((b << 10) + (yi << 5) + xi) * 256 + (g << 7) + c0];
        ac0 = fmaf(w, qv.x, ac0);
        ac1 = fmaf(w, qv.y, ac1);
      }
    }
  }
  *(unsigned*)&xsb[(size_t)((b << 10) + pix) * 256 + (g << 7) + c0] = pk2bf(ac0, ac1);
}

// ---------------------------------------------------------------------------
// Fused attention v5: barrier-free kt loop + fragment-packed K/V.
// Every MFMA B-operand load = base + lane*16B, CONTIGUOUS 1 KB per wave
// (8 beats, vs 16 scattered lines in v4).  All 8 K/V loads issued at the top
// of each kt so their latency overlaps the ~400-cycle sampling VALU.
// LDS = fp8 rpe quad table (16 KB) + wave-local P (9.2 KB) -> 6 blocks/CU.
// ---------------------------------------------------------------------------
__global__ __launch_bounds__(256, 6) void attn_kernel(
    const float* __restrict__ q, const short* __restrict__ kf,
    const short* __restrict__ vf, const float* __restrict__ pos,
    const float* __restrict__ rpe, short* __restrict__ ao)
{
  const int it = blockIdx.x, h = blockIdx.y, b = blockIdx.z;
  const int g = h >> 2, t = threadIdx.x;
  const int wv = t >> 6, l16 = t & 15, quad = (t & 63) >> 4;
  const int lane = t & 63;

  __shared__ __align__(16) short PL[64 * 72];       // P (wave-local rows)
  __shared__ __align__(16) unsigned rpe8[64 * 64];  // fp8 quad per point

  // ---- stage fp8 rpe quad table (origin +31; reachable window is 64x64)
  {
    const float* rp = rpe + h * 3969;
    for (int i = t; i < 4096; i += 256) {
      int ty = i >> 6, tx = i & 63;
      float v00 = 0.f, v10 = 0.f, v01 = 0.f, v11 = 0.f;
      if (tx <= 62) {
        if (ty <= 62) v00 = rp[ty * 63 + tx] * LOG2E;
        if (ty <= 61) v10 = rp[(ty + 1) * 63 + tx] * LOG2E;
      }
      if (tx <= 61) {
        if (ty <= 62) v01 = rp[ty * 63 + tx + 1] * LOG2E;
        if (ty <= 61) v11 = rp[(ty + 1) * 63 + tx + 1] * LOG2E;
      }
      __hip_fp8x2_e4m3 elo(make_float2(v00, v10));   // y-pair at x0
      __hip_fp8x2_e4m3 ehi(make_float2(v01, v11));   // y-pair at x0+1
      rpe8[i] = (unsigned)(unsigned short)elo.__x |
                ((unsigned)(unsigned short)ehi.__x << 16);
    }
  }

  // ---- Q A-frag from global (once), scaled by ASCALE*LOG2E
  const int row0 = (it << 6) + (wv << 4);
  bf16x8 aq;
  {
    const float* src = q + (size_t)((b << 10) + row0 + l16) * 256 + (h << 5) + (quad << 3);
    float4 f0 = *(const float4*)src;
    float4 f1 = *(const float4*)(src + 4);
    const float sc = ASCALE * LOG2E;
    union { unsigned u[4]; bf16x8 v; } c;
    c.u[0] = pk2bf(f0.x * sc, f0.y * sc); c.u[1] = pk2bf(f0.z * sc, f0.w * sc);
    c.u[2] = pk2bf(f1.x * sc, f1.y * sc); c.u[3] = pk2bf(f1.z * sc, f1.w * sc);
    aq = c.v;
  }

  // sampling coords (origin +31): wave's 16 rows share one raster row
  const float ayc = 15.5f * (((row0 >> 5) + 0.5f) * 0.0625f - 1.f) + 31.f;
  float ax[4];
#pragma unroll
  for (int r = 0; r < 4; r++) {
    int ix = (row0 & 31) + (quad << 2) + r;
    ax[r] = 15.5f * ((ix + 0.5f) * 0.0625f - 1.f) + 31.f;
  }

  bf16x8 vones;
#pragma unroll
  for (int i = 0; i < 8; i++) vones[i] = (short)0x3F80;  // bf16 1.0

  f32x4 Oacc[2] = {};
  f32x4 lacc = {};

  // fragment-packed bases for this (b,h): 16 kt * 4 frags * 512 shorts
  const short* kfB = kf + ((((size_t)(b << 3) + h) << 4) << 11) + (lane << 3);
  const short* vfB = vf + ((((size_t)(b << 3) + h) << 4) << 11) + (lane << 3);
  const float2* posB = ((const float2*)pos) + (((b << 1) + g) << 10) + l16;

  __syncthreads();  // rpe8 table ready; ONLY barrier in the kernel

  for (int kt = 0; kt < 16; kt++) {
    const int jb = kt << 6;

    // ---- issue ALL K/V fragment loads up front (coalesced 1 KB each)
    bf16x8 bk[4], vb[4];
#pragma unroll
    for (int jt = 0; jt < 4; jt++)
      bk[jt] = *(const bf16x8*)&kfB[((kt << 2) + jt) << 9];
#pragma unroll
    for (int u = 0; u < 4; u++)
      vb[u] = *(const bf16x8*)&vfB[((kt << 2) + u) << 9];

    // ---- QK^T: 4 MFMA
    f32x4 S[4];
#pragma unroll
    for (int jt = 0; jt < 4; jt++) {
      f32x4 z = {};
      S[jt] = __builtin_amdgcn_mfma_f32_16x16x32_bf16(aq, bk[jt], z, 0, 0, 0);
    }

    // ---- bias sample (1 b32 LDS gather/sample) + p = exp2(S+bias)
    unsigned pu[4][2];
#pragma unroll
    for (int jt = 0; jt < 4; jt++) {
      float2 pj = posB[jb + (jt << 4)];
      float ys = ayc - 15.5f * pj.x;
      float y0f = floorf(ys);
      float fy = ys - y0f;
      int ybase = (int)y0f << 6;
      float bx = -15.5f * pj.y;
      float pv[4];
#pragma unroll
      for (int r = 0; r < 4; r++) {
        float sx = ax[r] + bx;
        float x0f = floorf(sx);
        float fx = sx - x0f;
        unsigned u = rpe8[ybase + (int)x0f];
        __hip_fp8x2_e4m3 plo, phi;
        plo.__x = (__hip_fp8x2_storage_t)(unsigned short)(u & 0xffffu);
        phi.__x = (__hip_fp8x2_storage_t)(unsigned short)(u >> 16);
        float2 ga = (float2)plo;   // (g00, g10)
        float2 gb = (float2)phi;   // (g01, g11)
        float h0 = fmaf(fx, gb.x - ga.x, ga.x);
        float h1 = fmaf(fx, gb.y - ga.y, ga.y);
        float bias = fmaf(fy, h1 - h0, h0);
        pv[r] = exp2_fast(S[jt][r] + bias);
      }
      pu[jt][0] = pk2bf(pv[0], pv[1]);
      pu[jt][1] = pk2bf(pv[2], pv[3]);
    }

    // ---- wave-local P write -> A-frag read (no barrier needed)
#pragma unroll
    for (int jt = 0; jt < 4; jt++) {
      int cb = (jt << 4) + l16;
      int rb = ((wv << 4) + (quad << 2)) * 72 + cb;
      PL[rb]       = (short)(pu[jt][0] & 0xffff);
      PL[rb + 72]  = (short)(pu[jt][0] >> 16);
      PL[rb + 144] = (short)(pu[jt][1] & 0xffff);
      PL[rb + 216] = (short)(pu[jt][1] >> 16);
    }
    bf16x8 pa0 = *(const bf16x8*)&PL[((wv << 4) + l16) * 72 + (quad << 3)];
    bf16x8 pa1 = *(const bf16x8*)&PL[((wv << 4) + l16) * 72 + 32 + (quad << 3)];

    // ---- PV: 4 MFMA + l accumulation (2 MFMA)
#pragma unroll
    for (int dt = 0; dt < 2; dt++) {
      Oacc[dt] = __builtin_amdgcn_mfma_f32_16x16x32_bf16(pa0, vb[(dt << 1)],     Oacc[dt], 0, 0, 0);
      Oacc[dt] = __builtin_amdgcn_mfma_f32_16x16x32_bf16(pa1, vb[(dt << 1) + 1], Oacc[dt], 0, 0, 0);
    }
    lacc = __builtin_amdgcn_mfma_f32_16x16x32_bf16(pa0, vones, lacc, 0, 0, 0);
    lacc = __builtin_amdgcn_mfma_f32_16x16x32_bf16(pa1, vones, lacc, 0, 0, 0);
  }

  // ---- epilogue -> ao bf16
#pragma unroll
  for (int r = 0; r < 4; r++) {
    float inv = 1.f / lacc[r];
    int row = row0 + (quad << 2) + r;
#pragma unroll
    for (int dt = 0; dt < 2; dt++) {
      ao[(size_t)((b << 10) + row) * 256 + (h << 5) + (dt << 4) + l16] =
          f2bf(Oacc[dt][r] * inv);
    }
  }
}

// ---------------------------------------------------------------------------
extern "C" void kernel_launch(void* const* d_in, const int* in_sizes, int n_in,
                              void* d_out, int out_size, void* d_ws, size_t ws_size,
                              hipStream_t stream) {
  (void)in_sizes; (void)n_in; (void)out_size; (void)ws_size;
  const float* x      = (const float*)d_in[0];
  const float* Wq     = (const float*)d_in[1];
  const float* Wkv    = (const float*)d_in[2];
  const float* conv_w = (const float*)d_in[3];
  const float* conv_b = (const float*)d_in[4];
  const float* ln_g   = (const float*)d_in[5];
  const float* ln_b   = (const float*)d_in[6];
  const float* Woff   = (const float*)d_in[7];
  const float* rpe    = (const float*)d_in[8];
  const float* Wout   = (const float*)d_in[9];
  const float* bout   = (const float*)d_in[10];
  float* out = (float*)d_out;

  // disjoint workspace layout (float-slot offsets)
  float* ws    = (float*)d_ws;
  float* q     = ws;                        // [0,       2097152)
  float* pos   = ws + 2097152;              // [2097152, 2129920)
  short* kf    = (short*)(ws + 2129920);    // [2129920, 3178496) frag-packed K
  short* vf    = (short*)(ws + 3178496);    // [3178496, 4227072) frag-packed V^T
  short* xsb   = (short*)(ws + 4227072);    // [4227072, 5275648) 8192x256 bf16
  short* aob   = (short*)(ws + 5275648);    // [5275648, 6324224) 8192x256 bf16
  short* Wkvt  = (short*)(ws + 6324224);    // [6324224, 6389760) 512x256 bf16
  short* Woutt = (short*)(ws + 6389760);    // [6389760, 6422528) 256x256 bf16
  short* Wqt   = (short*)(ws + 6422528);    // [6422528, 6455296) 256x256 bf16

  prep_weights<<<1024, 256, 0, stream>>>(Wkv, Wout, Wq, Wkvt, Woutt, Wqt);
  // 1. q = x @ Wq (bf16 MFMA, f32 A staged+converted, f32 out)
  gemm_bf16<<<dim3(4, 128), 256, 0, stream>>>(nullptr, x, Wqt, q, nullptr, nullptr, 256, 0);
  // 2+3. conv + LN + GELU + Woff + tanh -> pos, fused grid_sample -> xs
  conv_pos_sample_kernel<<<4096, 256, 0, stream>>>(q, conv_w, conv_b, ln_g, ln_b,
                                                   Woff, pos, xsb);
  // 4a. K = xs @ Wkv[:, :256], fragment-packed output
  gemm_bf16<<<dim3(4, 128), 256, 0, stream>>>(xsb, nullptr, Wkvt, nullptr, kf, nullptr, 256, 1);
  // 4b. V^T = Wkv[:, 256:]^T @ xs^T, fragment-packed output
  gemm_bf16<<<dim3(128, 4), 256, 0, stream>>>(Wkvt + 256 * 256, nullptr, xsb,
                                              nullptr, vf, nullptr, 8192, 2);
  // 5. fused attention v5 (frag-packed operands) -> ao (bf16)
  attn_kernel<<<dim3(16, 8, 8), 256, 0, stream>>>(q, kf, vf, pos, rpe, aob);
  // 6. out = ao @ Wout + bout (bf16 MFMA, f32 out)
  gemm_bf16<<<dim3(4, 128), 256, 0, stream>>>(aob, nullptr, Woutt, out, nullptr, bout, 256, 0);
}

// Round 10
// 243.123 us; speedup vs baseline: 1.0746x; 1.0023x over previous
//
#include <hip/hip_runtime.h>
#include <hip/hip_bf16.h>
#include <hip/hip_fp16.h>
#include <hip/hip_fp8.h>

// DeformableAttention on MI355X.
// prep(weights^T bf16 + global fp8 rpe quad tables) -> gemm(q) ->
// conv+LN+GELU+pos+sample -> gemm(KV merged, frag-packed K and V^T outputs) ->
// flash-attn v6 (kt-split waves: 32 rows x 2 kt-halves per block, grid 2048 =
// 8 blocks/CU; rpe gathers from global L1/L2; barrier-free loop; additive
// O/l combine) -> gemm(out,+bias)

#define EPS_ 1e-5f
#define ASCALE 0.17677669529663687f      // 1/sqrt(32)
#define LOG2E  1.4426950408889634f

typedef __attribute__((ext_vector_type(8))) short bf16x8;
typedef __attribute__((ext_vector_type(4))) float f32x4;

__device__ __forceinline__ short f2bf(float f) {
  union { float f; unsigned u; } v; v.f = f;
  unsigned r = (v.u + 0x7fffu + ((v.u >> 16) & 1u)) >> 16;  // RNE
  return (short)r;
}
__device__ __forceinline__ unsigned pk2bf(float a, float b) {
  union { __hip_bfloat162 h; unsigned u; } v;
  v.h = __float22bfloat162_rn(make_float2(a, b));
  return v.u;
}
__device__ __forceinline__ float exp2_fast(float x) {
  return __builtin_amdgcn_exp2f(x);
}

// ---------------------------------------------------------------------------
// Prep: Wkvt/Woutt/Wqt transposed bf16 weights + global fp8 rpe quad tables.
// rpe8g[h*4096 + ty*64 + tx] = fp8 quad (g00,g10,g01,g11)*log2e at (ty,tx).
// ---------------------------------------------------------------------------
__global__ __launch_bounds__(256) void prep_weights(
    const float* __restrict__ Wkv, const float* __restrict__ Wout,
    const float* __restrict__ Wq, const float* __restrict__ rpe,
    short* __restrict__ Wkvt, short* __restrict__ Woutt,
    short* __restrict__ Wqt, unsigned* __restrict__ rpe8g)
{
  int bid = blockIdx.x, k = threadIdx.x;
  if (bid < 512) { Wkvt[bid * 256 + k] = f2bf(Wkv[k * 512 + bid]); return; }
  if (bid < 768) { int n = bid - 512; Woutt[n * 256 + k] = f2bf(Wout[k * 256 + n]); return; }
  if (bid < 1024) { int n = bid - 768; Wqt[n * 256 + k] = f2bf(Wq[k * 256 + n]); return; }
  int idx = ((bid - 1024) << 8) + k;      // 0..32767
  int h = idx >> 12, i = idx & 4095;
  int ty = i >> 6, tx = i & 63;
  const float* rp = rpe + h * 3969;
  float v00 = 0.f, v10 = 0.f, v01 = 0.f, v11 = 0.f;
  if (tx <= 62) {
    if (ty <= 62) v00 = rp[ty * 63 + tx] * LOG2E;
    if (ty <= 61) v10 = rp[(ty + 1) * 63 + tx] * LOG2E;
  }
  if (tx <= 61) {
    if (ty <= 62) v01 = rp[ty * 63 + tx + 1] * LOG2E;
    if (ty <= 61) v11 = rp[(ty + 1) * 63 + tx + 1] * LOG2E;
  }
  __hip_fp8x2_e4m3 elo(make_float2(v00, v10));   // y-pair at x0
  __hip_fp8x2_e4m3 ehi(make_float2(v01, v11));   // y-pair at x0+1
  rpe8g[idx] = (unsigned)(unsigned short)elo.__x |
               ((unsigned)(unsigned short)ehi.__x << 16);
}

// ---------------------------------------------------------------------------
// bf16 MFMA GEMM: C[M,N] = A[M,256] @ Bt[N,256]^T (+bias).
// Reg-prefetch + double-buffered LDS -> ONE barrier per K-chunk.
// mode 0: row-major out (Cf f32 or Cb bf16)
// mode 1: merged KV pack: ncol<256 -> K frag-pack into Cb; else V^T frag-pack
//         into Cb2.  Frag layout: element (n,k) of a 16x32 B-frag at
//         frag*512 + lane*8 + (k&7), lane = n + 16*(k>>3).
// ---------------------------------------------------------------------------
__global__ __launch_bounds__(256) void gemm_bf16(
    const short* __restrict__ Ab, const float* __restrict__ Af,
    const short* __restrict__ Bt,
    float* __restrict__ Cf, short* __restrict__ Cb, short* __restrict__ Cb2,
    const float* __restrict__ bias, int N, int mode)
{
  __shared__ __align__(16) short As[2][64 * 40];
  __shared__ __align__(16) short Bs[2][64 * 40];
  const int t = threadIdx.x;
  const int n0 = blockIdx.x << 6, m0 = blockIdx.y << 6;
  const int wv = t >> 6, l16 = t & 15, quad = (t & 63) >> 4;
  const int row = t >> 2, koff = (t & 3) << 3;

  auto loadA = [&](int k0) -> bf16x8 {
    if (Af) {
      const float* src = &Af[(size_t)(m0 + row) * 256 + k0 + koff];
      float4 f0 = *(const float4*)src;
      float4 f1 = *(const float4*)(src + 4);
      union { unsigned u[4]; bf16x8 v; } c;
      c.u[0] = pk2bf(f0.x, f0.y); c.u[1] = pk2bf(f0.z, f0.w);
      c.u[2] = pk2bf(f1.x, f1.y); c.u[3] = pk2bf(f1.z, f1.w);
      return c.v;
    }
    return *(const bf16x8*)&Ab[(size_t)(m0 + row) * 256 + k0 + koff];
  };

  f32x4 acc[4] = {};
  bf16x8 av = loadA(0);
  bf16x8 bv = *(const bf16x8*)&Bt[(size_t)(n0 + row) * 256 + koff];
  int pb = 0;
  for (int k0 = 0; k0 < 256; k0 += 32, pb ^= 1) {
    *(bf16x8*)&As[pb][row * 40 + koff] = av;
    *(bf16x8*)&Bs[pb][row * 40 + koff] = bv;
    __syncthreads();
    if (k0 + 32 < 256) {  // prefetch next chunk into regs during MFMA
      av = loadA(k0 + 32);
      bv = *(const bf16x8*)&Bt[(size_t)(n0 + row) * 256 + k0 + 32 + koff];
    }
    bf16x8 a = *(const bf16x8*)&As[pb][((wv << 4) + l16) * 40 + (quad << 3)];
#pragma unroll
    for (int jt = 0; jt < 4; jt++) {
      bf16x8 bb = *(const bf16x8*)&Bs[pb][((jt << 4) + l16) * 40 + (quad << 3)];
      acc[jt] = __builtin_amdgcn_mfma_f32_16x16x32_bf16(a, bb, acc[jt], 0, 0, 0);
    }
  }
#pragma unroll
  for (int jt = 0; jt < 4; jt++) {
#pragma unroll
    for (int r = 0; r < 4; r++) {
      int mrow = m0 + (wv << 4) + (quad << 2) + r;
      int ncol = n0 + (jt << 4) + l16;
      float v = acc[jt][r];
      if (mode == 0) {
        if (bias) v += bias[ncol];
        if (Cf) Cf[(size_t)mrow * N + ncol] = v;
        else    Cb[(size_t)mrow * N + ncol] = f2bf(v);
      } else {
        int b = mrow >> 10, j = mrow & 1023;
        if (ncol < 256) {
          // K pack
          int h = ncol >> 5, d = ncol & 31;
          size_t frag = ((((size_t)(b << 3) + h) << 4) + (j >> 6)) * 4 + ((j >> 4) & 3);
          Cb[(frag << 9) + ((((j & 15) | ((d >> 3) << 4))) << 3) + (d & 7)] = f2bf(v);
        } else {
          // V^T pack
          int nc = ncol - 256;
          int h = nc >> 5, d = nc & 31;
          size_t frag = (((((size_t)(b << 3) + h) << 4) + (j >> 6)) * 2 + ((d >> 4) & 1)) * 2 + ((j >> 5) & 1);
          Cb2[(frag << 9) + ((((d & 15) | (((j >> 3) & 3) << 4))) << 3) + (j & 7)] = f2bf(v);
        }
      }
    }
  }
}

// ---------------------------------------------------------------------------
// Fused: conv5x5 depthwise + LN(128) + GELU + @Woff + tanh -> pos, then
// grid_sample of this pixel's group channels -> xs (bf16). Wave per (b,g,pix).
// ---------------------------------------------------------------------------
__global__ __launch_bounds__(256) void conv_pos_sample_kernel(
    const float* __restrict__ q, const float* __restrict__ conv_w,
    const float* __restrict__ conv_b, const float* __restrict__ ln_g,
    const float* __restrict__ ln_b, const float* __restrict__ Woff,
    float* __restrict__ pos, short* __restrict__ xsb)
{
  const int p = (blockIdx.x << 2) + (threadIdx.x >> 6);
  const int lane = threadIdx.x & 63;
  const int bg = p >> 10, pix = p & 1023;
  const int hh = pix >> 5, ww = pix & 31;
  const int b = bg >> 1, g = bg & 1;
  const int c0 = lane << 1;

  float2 cb = *(const float2*)&conv_b[c0];
  float a0 = cb.x, a1 = cb.y;
  const float* w0 = conv_w + c0 * 25;
  const float* w1 = w0 + 25;
#pragma unroll
  for (int dy = 0; dy < 5; dy++) {
    int y = hh + dy - 2;
    if ((unsigned)y < 32u) {
#pragma unroll
      for (int dx = 0; dx < 5; dx++) {
        int x = ww + dx - 2;
        if ((unsigned)x < 32u) {
          float2 qv = *(const float2*)&q[(size_t)((b << 10) + (y << 5) + x) * 256 + (g << 7) + c0];
          a0 = fmaf(qv.x, w0[dy * 5 + dx], a0);
          a1 = fmaf(qv.y, w1[dy * 5 + dx], a1);
        }
      }
    }
  }
  float s1 = a0 + a1, s2 = a0 * a0 + a1 * a1;
#pragma unroll
  for (int o = 32; o; o >>= 1) { s1 += __shfl_xor(s1, o); s2 += __shfl_xor(s2, o); }
  float mu = s1 * (1.f / 128.f);
  float inv = rsqrtf(fmaf(-mu, mu, s2 * (1.f / 128.f)) + EPS_);
  float2 lg = *(const float2*)&ln_g[c0];
  float2 lb = *(const float2*)&ln_b[c0];
  float v0 = (a0 - mu) * inv * lg.x + lb.x;
  float v1 = (a1 - mu) * inv * lg.y + lb.y;
  float ge0 = 0.5f * v0 * (1.f + erff(v0 * 0.70710678118654752f));
  float ge1 = 0.5f * v1 * (1.f + erff(v1 * 0.70710678118654752f));
  float2 W0 = *(const float2*)&Woff[c0 * 2];
  float2 W1 = *(const float2*)&Woff[c0 * 2 + 2];
  float o0 = ge0 * W0.x + ge1 * W1.x;
  float o1 = ge0 * W0.y + ge1 * W1.y;
#pragma unroll
  for (int o = 32; o; o >>= 1) { o0 += __shfl_xor(o0, o); o1 += __shfl_xor(o1, o); }
  float py = tanhf(o0) * 0.0625f + ((hh + 0.5f) * 0.0625f - 1.f);
  float px = tanhf(o1) * 0.0625f + ((ww + 0.5f) * 0.0625f - 1.f);
  if (lane == 0)
    ((float2*)pos)[(bg << 10) + pix] = make_float2(py, px);

  float x = (px + 1.f) * 15.5f;
  float y = (py + 1.f) * 15.5f;
  float x0f = floorf(x), y0f = floorf(y);
  int ix0 = (int)x0f, iy0 = (int)y0f;
  float fx = x - x0f, fy = y - y0f;
  float ac0 = 0.f, ac1 = 0.f;
#pragma unroll
  for (int dy = 0; dy < 2; dy++) {
#pragma unroll
    for (int dx = 0; dx < 2; dx++) {
      int yi = iy0 + dy, xi = ix0 + dx;
      float w = (dy ? fy : 1.f - fy) * (dx ? fx : 1.f - fx);
      if ((unsigned)yi < 32u && (unsigned)xi < 32u) {
        float2 qv = *(const float2*)&q[(size_t)((b << 10) + (yi << 5) + xi) * 256 + (g << 7) + c0];
        ac0 = fmaf(w, qv.x, ac0);
        ac1 = fmaf(w, qv.y, ac1);
      }
    }
  }
  *(unsigned*)&xsb[(size_t)((b << 10) + pix) * 256 + (g << 7) + c0] = pk2bf(ac0, ac1);
}

// ---------------------------------------------------------------------------
// Fused attention v6: kt-split waves for occupancy.
// Block = (32-row i-tile, head, batch), grid 32x8x8 = 2048 = 8 blocks/CU.
// 4 waves: rg = wv&1 (16-row group), hf = wv>>1 (kt half 0-7 / 8-15).
// Fixed-m softmax is additive across kt -> halves combine by O+=O', l+=l'.
// rpe gathers from GLOBAL fp8 quad table (L1/L2-hot, no LDS copy).
// LDS = wave-local P only (18.4 KB) -> 8 blocks/CU possible.
// No barrier in the kt loop; 2 barriers for the additive combine.
// ---------------------------------------------------------------------------
__global__ __launch_bounds__(256, 8) void attn_kernel(
    const float* __restrict__ q, const short* __restrict__ kf,
    const short* __restrict__ vf, const float* __restrict__ pos,
    const unsigned* __restrict__ rpe8g, short* __restrict__ ao)
{
  const int it = blockIdx.x, h = blockIdx.y, b = blockIdx.z;
  const int g = h >> 2, t = threadIdx.x;
  const int wv = t >> 6, l16 = t & 15, quad = (t & 63) >> 4;
  const int lane = t & 63;
  const int rg = wv & 1, hf = wv >> 1;

  __shared__ __align__(16) short PL[64 * 72];   // per-wave 16-row P regions

  // ---- Q A-frag from global (once), scaled by ASCALE*LOG2E
  const int row0 = (it << 5) + (rg << 4);
  bf16x8 aq;
  {
    const float* src = q + (size_t)((b << 10) + row0 + l16) * 256 + (h << 5) + (quad << 3);
    float4 f0 = *(const float4*)src;
    float4 f1 = *(const float4*)(src + 4);
    const float sc = ASCALE * LOG2E;
    union { unsigned u[4]; bf16x8 v; } c;
    c.u[0] = pk2bf(f0.x * sc, f0.y * sc); c.u[1] = pk2bf(f0.z * sc, f0.w * sc);
    c.u[2] = pk2bf(f1.x * sc, f1.y * sc); c.u[3] = pk2bf(f1.z * sc, f1.w * sc);
    aq = c.v;
  }

  // sampling coords (origin +31): wave's 16 rows share one raster row
  const float ayc = 15.5f * (((row0 >> 5) + 0.5f) * 0.0625f - 1.f) + 31.f;
  float ax[4];
#pragma unroll
  for (int r = 0; r < 4; r++) {
    int ix = (row0 & 31) + (quad << 2) + r;
    ax[r] = 15.5f * ((ix + 0.5f) * 0.0625f - 1.f) + 31.f;
  }

  bf16x8 vones;
#pragma unroll
  for (int i = 0; i < 8; i++) vones[i] = (short)0x3F80;  // bf16 1.0

  f32x4 Oacc[2] = {};
  f32x4 lacc = {};

  // fragment-packed bases for this (b,h)
  const short* kfB = kf + ((((size_t)(b << 3) + h) << 4) << 11) + (lane << 3);
  const short* vfB = vf + ((((size_t)(b << 3) + h) << 4) << 11) + (lane << 3);
  const float2* posB = ((const float2*)pos) + (((b << 1) + g) << 10) + l16;
  const unsigned* rpeT = rpe8g + (h << 12);

  for (int kt = hf << 3; kt < (hf << 3) + 8; kt++) {
    const int jb = kt << 6;

    // ---- issue all K/V frag loads + pos loads up front
    bf16x8 bk[4], vb[4];
    float2 pj[4];
#pragma unroll
    for (int jt = 0; jt < 4; jt++)
      bk[jt] = *(const bf16x8*)&kfB[((kt << 2) + jt) << 9];
#pragma unroll
    for (int u = 0; u < 4; u++)
      vb[u] = *(const bf16x8*)&vfB[((kt << 2) + u) << 9];
#pragma unroll
    for (int jt = 0; jt < 4; jt++)
      pj[jt] = posB[jb + (jt << 4)];

    // ---- QK^T: 4 MFMA
    f32x4 S[4];
#pragma unroll
    for (int jt = 0; jt < 4; jt++) {
      f32x4 z = {};
      S[jt] = __builtin_amdgcn_mfma_f32_16x16x32_bf16(aq, bk[jt], z, 0, 0, 0);
    }

    // ---- bias sample (1 global b32 gather/sample, L1/L2-hot) + exp2
    unsigned pu[4][2];
#pragma unroll
    for (int jt = 0; jt < 4; jt++) {
      float ys = ayc - 15.5f * pj[jt].x;
      float y0f = floorf(ys);
      float fy = ys - y0f;
      int ybase = (int)y0f << 6;
      float bx = -15.5f * pj[jt].y;
      float pv[4];
#pragma unroll
      for (int r = 0; r < 4; r++) {
        float sx = ax[r] + bx;
        float x0f = floorf(sx);
        float fx = sx - x0f;
        unsigned u = rpeT[ybase + (int)x0f];
        __hip_fp8x2_e4m3 plo, phi;
        plo.__x = (__hip_fp8x2_storage_t)(unsigned short)(u & 0xffffu);
        phi.__x = (__hip_fp8x2_storage_t)(unsigned short)(u >> 16);
        float2 ga = (float2)plo;   // (g00, g10)
        float2 gb = (float2)phi;   // (g01, g11)
        float h0 = fmaf(fx, gb.x - ga.x, ga.x);
        float h1 = fmaf(fx, gb.y - ga.y, ga.y);
        float bias = fmaf(fy, h1 - h0, h0);
        pv[r] = exp2_fast(S[jt][r] + bias);
      }
      pu[jt][0] = pk2bf(pv[0], pv[1]);
      pu[jt][1] = pk2bf(pv[2], pv[3]);
    }

    // ---- wave-local P write -> A-frag read (no barrier)
#pragma unroll
    for (int jt = 0; jt < 4; jt++) {
      int cb = (jt << 4) + l16;
      int rb = ((wv << 4) + (quad << 2)) * 72 + cb;
      PL[rb]       = (short)(pu[jt][0] & 0xffff);
      PL[rb + 72]  = (short)(pu[jt][0] >> 16);
      PL[rb + 144] = (short)(pu[jt][1] & 0xffff);
      PL[rb + 216] = (short)(pu[jt][1] >> 16);
    }
    bf16x8 pa0 = *(const bf16x8*)&PL[((wv << 4) + l16) * 72 + (quad << 3)];
    bf16x8 pa1 = *(const bf16x8*)&PL[((wv << 4) + l16) * 72 + 32 + (quad << 3)];

    // ---- PV: 4 MFMA + l accumulation (2 MFMA)
#pragma unroll
    for (int dt = 0; dt < 2; dt++) {
      Oacc[dt] = __builtin_amdgcn_mfma_f32_16x16x32_bf16(pa0, vb[(dt << 1)],     Oacc[dt], 0, 0, 0);
      Oacc[dt] = __builtin_amdgcn_mfma_f32_16x16x32_bf16(pa1, vb[(dt << 1) + 1], Oacc[dt], 0, 0, 0);
    }
    lacc = __builtin_amdgcn_mfma_f32_16x16x32_bf16(pa0, vones, lacc, 0, 0, 0);
    lacc = __builtin_amdgcn_mfma_f32_16x16x32_bf16(pa1, vones, lacc, 0, 0, 0);
  }

  // ---- additive combine of the two kt-halves (overlay PL as float scratch)
  __syncthreads();                 // all PV reads of PL done
  float* cbuf = (float*)PL;        // 128 slots x 12 floats = 6 KB < 18.4 KB
  const int slot = ((rg << 6) + lane) * 12;
  if (hf == 1) {
    *(f32x4*)&cbuf[slot]     = Oacc[0];
    *(f32x4*)&cbuf[slot + 4] = Oacc[1];
    *(f32x4*)&cbuf[slot + 8] = lacc;
  }
  __syncthreads();
  if (hf == 0) {
    f32x4 o0 = *(const f32x4*)&cbuf[slot];
    f32x4 o1 = *(const f32x4*)&cbuf[slot + 4];
    f32x4 lx = *(const f32x4*)&cbuf[slot + 8];
#pragma unroll
    for (int r = 0; r < 4; r++) {
      float inv = 1.f / (lacc[r] + lx[r]);
      int row = row0 + (quad << 2) + r;
      ao[(size_t)((b << 10) + row) * 256 + (h << 5) + l16] =
          f2bf((Oacc[0][r] + o0[r]) * inv);
      ao[(size_t)((b << 10) + row) * 256 + (h << 5) + 16 + l16] =
          f2bf((Oacc[1][r] + o1[r]) * inv);
    }
  }
}

// ---------------------------------------------------------------------------
extern "C" void kernel_launch(void* const* d_in, const int* in_sizes, int n_in,
                              void* d_out, int out_size, void* d_ws, size_t ws_size,
                              hipStream_t stream) {
  (void)in_sizes; (void)n_in; (void)out_size; (void)ws_size;
  const float* x      = (const float*)d_in[0];
  const float* Wq     = (const float*)d_in[1];
  const float* Wkv    = (const float*)d_in[2];
  const float* conv_w = (const float*)d_in[3];
  const float* conv_b = (const float*)d_in[4];
  const float* ln_g   = (const float*)d_in[5];
  const float* ln_b   = (const float*)d_in[6];
  const float* Woff   = (const float*)d_in[7];
  const float* rpe    = (const float*)d_in[8];
  const float* Wout   = (const float*)d_in[9];
  const float* bout   = (const float*)d_in[10];
  float* out = (float*)d_out;

  // disjoint workspace layout (float-slot offsets)
  float* ws    = (float*)d_ws;
  float* q     = ws;                        // [0,       2097152)
  float* pos   = ws + 2097152;              // [2097152, 2129920)
  short* kf    = (short*)(ws + 2129920);    // [2129920, 3178496) frag-packed K
  short* vf    = (short*)(ws + 3178496);    // [3178496, 4227072) frag-packed V^T
  short* xsb   = (short*)(ws + 4227072);    // [4227072, 5275648) 8192x256 bf16
  short* aob   = (short*)(ws + 5275648);    // [5275648, 6324224) 8192x256 bf16
  short* Wkvt  = (short*)(ws + 6324224);    // [6324224, 6389760) 512x256 bf16
  short* Woutt = (short*)(ws + 6389760);    // [6389760, 6422528) 256x256 bf16
  short* Wqt   = (short*)(ws + 6422528);    // [6422528, 6455296) 256x256 bf16
  unsigned* rpe8g = (unsigned*)(ws + 6455296); // [6455296, 6488064) 8x4096 u32

  prep_weights<<<1152, 256, 0, stream>>>(Wkv, Wout, Wq, rpe, Wkvt, Woutt, Wqt, rpe8g);
  // 1. q = x @ Wq (bf16 MFMA, f32 A staged+converted, f32 out)
  gemm_bf16<<<dim3(4, 128), 256, 0, stream>>>(nullptr, x, Wqt, q, nullptr, nullptr, nullptr, 256, 0);
  // 2+3. conv + LN + GELU + Woff + tanh -> pos, fused grid_sample -> xs
  conv_pos_sample_kernel<<<4096, 256, 0, stream>>>(q, conv_w, conv_b, ln_g, ln_b,
                                                   Woff, pos, xsb);
  // 4. merged KV GEMM: K frag-pack + V^T frag-pack in one pass
  gemm_bf16<<<dim3(8, 128), 256, 0, stream>>>(xsb, nullptr, Wkvt, nullptr, kf, vf, nullptr, 512, 1);
  // 5. fused attention v6 (kt-split, global rpe) -> ao (bf16)
  attn_kernel<<<dim3(32, 8, 8), 256, 0, stream>>>(q, kf, vf, pos, rpe8g, aob);
  // 6. out = ao @ Wout + bout (bf16 MFMA, f32 out)
  gemm_bf16<<<dim3(4, 128), 256, 0, stream>>>(aob, nullptr, Woutt, out, nullptr, nullptr, bout, 256, 0);
}